// Round 5
// baseline (749.006 us; speedup 1.0000x reference)
//
#include <hip/hip_runtime.h>

typedef __bf16 bf16x8 __attribute__((ext_vector_type(8)));
typedef float f32x16 __attribute__((ext_vector_type(16)));

#define DEV static __device__ __forceinline__
#define MFMA(a, b, c) __builtin_amdgcn_mfma_f32_32x32x16_bf16((a), (b), (c), 0, 0, 0)

DEV unsigned short f2bf(float f) {
  unsigned u = __float_as_uint(f);
  unsigned r = u + 0x7fffu + ((u >> 16) & 1u);
  return (unsigned short)(r >> 16);
}
DEV float bflo(unsigned u) { return __uint_as_float(u << 16); }
DEV float bfhi(unsigned u) { return __uint_as_float(u & 0xffff0000u); }

DEV f32x16 zero16() {
  f32x16 z;
#pragma unroll
  for (int i = 0; i < 16; i++) z[i] = 0.f;
  return z;
}

// LDS fragment read helpers. Rows are XOR-swizzled by granule^(row&7).
DEV bf16x8 frag256(const unsigned short* lds, int rowbase, int l, int kk) {
  int row = rowbase + (l & 31);
  int gran = (kk << 1) + (l >> 5);
  return *reinterpret_cast<const bf16x8*>(&lds[row * 128 + ((gran ^ (row & 7)) << 3)]);
}

// ---------------- transpose + f32->bf16 convert: in[R][C] f32 -> out[C][R] bf16
__global__ void k_transpose(const float* __restrict__ in, unsigned short* __restrict__ out,
                            int R, int C) {
  __shared__ float t[32][33];
  int tx = threadIdx.x, ty = threadIdx.y;
  int c0 = blockIdx.x * 32, r0 = blockIdx.y * 32;
#pragma unroll
  for (int i = 0; i < 4; i++)
    t[ty + i * 8][tx] = in[(size_t)(r0 + ty + i * 8) * C + c0 + tx];
  __syncthreads();
#pragma unroll
  for (int i = 0; i < 4; i++)
    out[(size_t)(c0 + ty + i * 8) * R + r0 + tx] = f2bf(t[tx][ty + i * 8]);
}

// ---------------- build Wqkv_t [384][128] and Wo_t [128][128]
__global__ void k_build_qkvo(const float* __restrict__ Wq, const float* __restrict__ Wk,
                             const float* __restrict__ Wv, const float* __restrict__ Wo,
                             unsigned short* __restrict__ qkvt, unsigned short* __restrict__ wot) {
  int gid = blockIdx.x * 256 + threadIdx.x;
  if (gid < 49152) {
    int row = gid >> 7, e = gid & 127;
    int mi = row >> 7, c = row & 127, h = c >> 4, d = c & 15;
    const float* W = (mi == 0) ? Wq : (mi == 1) ? Wk : Wv;
    qkvt[gid] = f2bf(W[(h * 128 + e) * 16 + d]);
  } else {
    int id = gid - 49152;
    int n = id >> 7, k = id & 127;
    wot[id] = f2bf(Wo[k * 128 + n]);
  }
}

// ---------------- LayerNorm: one wave per 128-wide row, out bf16
__global__ void k_ln(const float* __restrict__ x, const float* __restrict__ g,
                     const float* __restrict__ b, unsigned short* __restrict__ out) {
  int row = blockIdx.x * 4 + (threadIdx.x >> 6);
  int l = threadIdx.x & 63;
  const float* xr = x + (size_t)row * 128;
  float x0 = xr[l * 2], x1v = xr[l * 2 + 1];
  float s = x0 + x1v;
#pragma unroll
  for (int m = 1; m < 64; m <<= 1) s += __shfl_xor(s, m, 64);
  float mu = s * 0.0078125f;
  float d0 = x0 - mu, d1 = x1v - mu;
  float ss = d0 * d0 + d1 * d1;
#pragma unroll
  for (int m = 1; m < 64; m <<= 1) ss += __shfl_xor(ss, m, 64);
  float inv = rsqrtf(ss * 0.0078125f + 1e-5f);
  float y0 = d0 * inv * g[l * 2] + b[l * 2];
  float y1 = d1 * inv * g[l * 2 + 1] + b[l * 2 + 1];
  unsigned u = ((unsigned)f2bf(y1) << 16) | (unsigned)f2bf(y0);
  *reinterpret_cast<unsigned*>(out + (size_t)row * 128 + l * 2) = u;
}

// ---------------- QKV projection
__global__ void k_gemm_qkv(const unsigned short* __restrict__ A, const unsigned short* __restrict__ Bt,
                           unsigned short* __restrict__ qkv) {
  __shared__ __align__(16) unsigned short As[128 * 128];
  __shared__ __align__(16) unsigned short Bs[128 * 128];
  int tid = threadIdx.x;
  int m0 = blockIdx.x * 128, n0 = blockIdx.y * 128;
  int sg = tid & 15, sr = tid >> 4;
#pragma unroll
  for (int i = 0; i < 8; i++) {
    int r = sr + i * 16;
    *reinterpret_cast<bf16x8*>(&As[r * 128 + ((sg ^ (r & 7)) << 3)]) =
        *reinterpret_cast<const bf16x8*>(A + (size_t)(m0 + r) * 128 + sg * 8);
    *reinterpret_cast<bf16x8*>(&Bs[r * 128 + ((sg ^ (r & 7)) << 3)]) =
        *reinterpret_cast<const bf16x8*>(Bt + (size_t)(n0 + r) * 128 + sg * 8);
  }
  __syncthreads();
  int l = tid & 63, w = tid >> 6, wmi = w >> 1, wni = w & 1;
  int ln = l & 31, hi = l >> 5;
  f32x16 acc[2][2];
  acc[0][0] = zero16(); acc[0][1] = zero16(); acc[1][0] = zero16(); acc[1][1] = zero16();
#pragma unroll
  for (int kk = 0; kk < 8; kk++) {
    bf16x8 a0 = frag256(As, wmi * 64, l, kk);
    bf16x8 a1 = frag256(As, wmi * 64 + 32, l, kk);
    bf16x8 b0 = frag256(Bs, wni * 64, l, kk);
    bf16x8 b1 = frag256(Bs, wni * 64 + 32, l, kk);
    acc[0][0] = MFMA(a0, b0, acc[0][0]);
    acc[0][1] = MFMA(a0, b1, acc[0][1]);
    acc[1][0] = MFMA(a1, b0, acc[1][0]);
    acc[1][1] = MFMA(a1, b1, acc[1][1]);
  }
  unsigned short* mat = qkv + (size_t)blockIdx.y * 524288;
#pragma unroll
  for (int im = 0; im < 2; im++)
#pragma unroll
    for (int in_ = 0; in_ < 2; in_++) {
      int c = wni * 64 + in_ * 32 + ln;
      int h = c >> 4, d = c & 15;
#pragma unroll
      for (int r = 0; r < 16; r++) {
        int m = m0 + wmi * 64 + im * 32 + (r & 3) + ((r >> 2) << 3) + (hi << 2);
        int bb = m >> 11, tt = m & 2047;
        mat[((size_t)((bb << 3) + h) * 2048 + tt) * 16 + d] = f2bf(acc[im][in_][r]);
      }
    }
}

// ---------------- MFMA flash attention (swapped QK^T, transposed PV) ----------------
DEV bf16x8 pfrag(float a0, float a1, float a2, float a3,
                 float a4, float a5, float a6, float a7) {
  unsigned c0, c1, c2, c3;
  asm("v_cvt_pk_bf16_f32 %0, %1, %2" : "=v"(c0) : "v"(a0), "v"(a1));
  asm("v_cvt_pk_bf16_f32 %0, %1, %2" : "=v"(c1) : "v"(a2), "v"(a3));
  asm("v_cvt_pk_bf16_f32 %0, %1, %2" : "=v"(c2) : "v"(a4), "v"(a5));
  asm("v_cvt_pk_bf16_f32 %0, %1, %2" : "=v"(c3) : "v"(a6), "v"(a7));
  asm("v_permlane32_swap_b32 %0, %1" : "+v"(c0), "+v"(c2));
  asm("v_permlane32_swap_b32 %0, %1" : "+v"(c1), "+v"(c3));
  int4 ri = make_int4((int)c0, (int)c1, (int)c2, (int)c3);
  return *reinterpret_cast<bf16x8*>(&ri);
}

__global__ void __launch_bounds__(256)
k_attn2(const unsigned short* __restrict__ qw, const unsigned short* __restrict__ kw,
        const unsigned short* __restrict__ vw, unsigned short* __restrict__ ow) {
  __shared__ __align__(16) unsigned short vt[2][16][72];  // V^T, padded rows (2-way banks)
  int tid = threadIdx.x;
  int qb = (int)gridDim.x - 1 - (int)blockIdx.x;  // heaviest q-tiles first
  int bh = blockIdx.y;
  int w = tid >> 6, l = tid & 63, ln = l & 31, hi = l >> 5;
  int q0 = qb * 128 + w * 32;
  int q = q0 + ln;
  const float SC = 0.08838834764831845f * 1.4426950408889634f;  // E^-0.5 * log2(e)
  const unsigned short* kbase = kw + (size_t)bh * 32768;
  const unsigned short* vbase = vw + (size_t)bh * 32768;
  // Q as B-operand: lane holds Q[q0+ln][hi*8 + i]
  bf16x8 qf = *reinterpret_cast<const bf16x8*>(qw + (size_t)bh * 32768 + (size_t)q * 16 + hi * 8);
  f32x16 acc = zero16();
  float mr = -1e30f, ls = 0.f;
  int ntiles = 2 * qb + 2;
  int skey = tid >> 1, sh = tid & 1;
  for (int st = 0; st < ntiles; st++) {
    int k0 = st * 64;
    int buf = st & 1;
    if (tid < 128) {  // stage V^T [16][64] for this tile
      const unsigned* vp = reinterpret_cast<const unsigned*>(vbase + (size_t)(k0 + skey) * 16 + sh * 8);
      unsigned u0 = vp[0], u1 = vp[1], u2 = vp[2], u3 = vp[3];
      int d0 = sh * 8;
      vt[buf][d0 + 0][skey] = (unsigned short)u0;
      vt[buf][d0 + 1][skey] = (unsigned short)(u0 >> 16);
      vt[buf][d0 + 2][skey] = (unsigned short)u1;
      vt[buf][d0 + 3][skey] = (unsigned short)(u1 >> 16);
      vt[buf][d0 + 4][skey] = (unsigned short)u2;
      vt[buf][d0 + 5][skey] = (unsigned short)(u2 >> 16);
      vt[buf][d0 + 6][skey] = (unsigned short)u3;
      vt[buf][d0 + 7][skey] = (unsigned short)(u3 >> 16);
    }
    __syncthreads();
    if (k0 > q0 + 31) continue;            // this wave's q-range done with these keys
    bool d1 = (k0 + 32 <= q0 + 31);        // need second 32-key subtile?
    f32x16 p0, p1;
    {
      bf16x8 ka = *reinterpret_cast<const bf16x8*>(kbase + (size_t)(k0 + ln) * 16 + hi * 8);
      p0 = MFMA(ka, qf, zero16());         // S^T: col=q, rows=keys
    }
    if (d1) {
      bf16x8 kb = *reinterpret_cast<const bf16x8*>(kbase + (size_t)(k0 + 32 + ln) * 16 + hi * 8);
      p1 = MFMA(kb, qf, zero16());
    }
    if (k0 + 31 > q0) {                    // subtile 1 overlaps diagonal: causal mask
#pragma unroll
      for (int r = 0; r < 16; r++) {
        int krow = (r & 3) + 8 * (r >> 2) + 4 * hi;
        if (k0 + krow > q) p0[r] = -1e30f;
      }
    }
    if (d1 && (k0 + 63 > q0)) {            // subtile 2 overlaps diagonal: causal mask
#pragma unroll
      for (int r = 0; r < 16; r++) {
        int krow = (r & 3) + 8 * (r >> 2) + 4 * hi;
        if (k0 + 32 + krow > q) p1[r] = -1e30f;
      }
    }
    // online softmax (raw scores; scale folded into exp2 arg)
    float tm = p0[0];
#pragma unroll
    for (int r = 1; r < 16; r++) tm = fmaxf(tm, p0[r]);
    if (d1) {
#pragma unroll
      for (int r = 0; r < 16; r++) tm = fmaxf(tm, p1[r]);
    }
    tm = fmaxf(tm, __shfl_xor(tm, 32, 64));
    if (tm > mr) {
      float corr = exp2f((mr - tm) * SC);
      ls *= corr;
#pragma unroll
      for (int r = 0; r < 8; r++) acc[r] *= corr;
      mr = tm;
    }
    float msc = mr * SC;
#pragma unroll
    for (int r = 0; r < 16; r++) {
      p0[r] = exp2f(fmaf(p0[r], SC, -msc));
      ls += p0[r];
    }
    if (d1) {
#pragma unroll
      for (int r = 0; r < 16; r++) {
        p1[r] = exp2f(fmaf(p1[r], SC, -msc));
        ls += p1[r];
      }
    }
    // PV: O^T += V^T * P^T  (A rows 16-31 duplicate d&15; D rows 16-31 unused)
    const unsigned short* vrow = &vt[buf][ln & 15][0];
    {
      bf16x8 pa = pfrag(p0[0], p0[1], p0[2], p0[3], p0[4], p0[5], p0[6], p0[7]);
      bf16x8 va = *reinterpret_cast<const bf16x8*>(vrow + hi * 8);
      acc = MFMA(va, pa, acc);
      pa = pfrag(p0[8], p0[9], p0[10], p0[11], p0[12], p0[13], p0[14], p0[15]);
      va = *reinterpret_cast<const bf16x8*>(vrow + 16 + hi * 8);
      acc = MFMA(va, pa, acc);
    }
    if (d1) {
      bf16x8 pa = pfrag(p1[0], p1[1], p1[2], p1[3], p1[4], p1[5], p1[6], p1[7]);
      bf16x8 va = *reinterpret_cast<const bf16x8*>(vrow + 32 + hi * 8);
      acc = MFMA(va, pa, acc);
      pa = pfrag(p1[8], p1[9], p1[10], p1[11], p1[12], p1[13], p1[14], p1[15]);
      va = *reinterpret_cast<const bf16x8*>(vrow + 48 + hi * 8);
      acc = MFMA(va, pa, acc);
    }
  }
  ls += __shfl_xor(ls, 32, 64);
  float rl = 1.0f / ls;
  int b_ = bh >> 3, h_ = bh & 7;
  unsigned short* op = ow + ((size_t)(b_ * 2048 + q)) * 128 + h_ * 16;
  int dbase = 4 * hi;  // acc rows r=0..7 -> d = (r&3) + 8*(r>>2) + 4*hi
  unsigned o0 = ((unsigned)f2bf(acc[1] * rl) << 16) | (unsigned)f2bf(acc[0] * rl);
  unsigned o1 = ((unsigned)f2bf(acc[3] * rl) << 16) | (unsigned)f2bf(acc[2] * rl);
  unsigned o2 = ((unsigned)f2bf(acc[5] * rl) << 16) | (unsigned)f2bf(acc[4] * rl);
  unsigned o3 = ((unsigned)f2bf(acc[7] * rl) << 16) | (unsigned)f2bf(acc[6] * rl);
  *reinterpret_cast<unsigned*>(op + dbase) = o0;
  *reinterpret_cast<unsigned*>(op + dbase + 2) = o1;
  *reinterpret_cast<unsigned*>(op + 8 + dbase) = o2;
  *reinterpret_cast<unsigned*>(op + 8 + dbase + 2) = o3;
}

// ---------------- output projection + residual
__global__ void k_gemm_proj(const unsigned short* __restrict__ A, const unsigned short* __restrict__ Bt,
                            const float* __restrict__ bo, const float* __restrict__ x,
                            const float* __restrict__ bf2, float* __restrict__ x1,
                            float* __restrict__ outp) {
  __shared__ __align__(16) unsigned short As[128 * 128];
  __shared__ __align__(16) unsigned short Bs[128 * 128];
  int tid = threadIdx.x;
  int m0 = blockIdx.x * 128;
  int sg = tid & 15, sr = tid >> 4;
#pragma unroll
  for (int i = 0; i < 8; i++) {
    int r = sr + i * 16;
    *reinterpret_cast<bf16x8*>(&As[r * 128 + ((sg ^ (r & 7)) << 3)]) =
        *reinterpret_cast<const bf16x8*>(A + (size_t)(m0 + r) * 128 + sg * 8);
    *reinterpret_cast<bf16x8*>(&Bs[r * 128 + ((sg ^ (r & 7)) << 3)]) =
        *reinterpret_cast<const bf16x8*>(Bt + (size_t)r * 128 + sg * 8);
  }
  __syncthreads();
  int l = tid & 63, w = tid >> 6, wmi = w >> 1, wni = w & 1;
  int ln = l & 31, hi = l >> 5;
  f32x16 acc[2][2];
  acc[0][0] = zero16(); acc[0][1] = zero16(); acc[1][0] = zero16(); acc[1][1] = zero16();
#pragma unroll
  for (int kk = 0; kk < 8; kk++) {
    bf16x8 a0 = frag256(As, wmi * 64, l, kk);
    bf16x8 a1 = frag256(As, wmi * 64 + 32, l, kk);
    bf16x8 b0 = frag256(Bs, wni * 64, l, kk);
    bf16x8 b1 = frag256(Bs, wni * 64 + 32, l, kk);
    acc[0][0] = MFMA(a0, b0, acc[0][0]);
    acc[0][1] = MFMA(a0, b1, acc[0][1]);
    acc[1][0] = MFMA(a1, b0, acc[1][0]);
    acc[1][1] = MFMA(a1, b1, acc[1][1]);
  }
#pragma unroll
  for (int im = 0; im < 2; im++)
#pragma unroll
    for (int in_ = 0; in_ < 2; in_++) {
      int n = wni * 64 + in_ * 32 + ln;
      float bon = bo[n], b2n = bf2[n];
#pragma unroll
      for (int r = 0; r < 16; r++) {
        int m = m0 + wmi * 64 + im * 32 + (r & 3) + ((r >> 2) << 3) + (hi << 2);
        float v = acc[im][in_][r] + bon;
        float xv = x[(size_t)m * 128 + n] + v;
        x1[(size_t)m * 128 + n] = xv;
        outp[(size_t)m * 128 + n] = xv + b2n;
      }
    }
}

// ---------------- fused FFN v2: out += relu(h2@W1+bf1)@W2
// Transposed GEMM1 (Gt = W1t-as-A x h2-as-B) keeps hidden axis in registers;
// relu+bias in-register; pfrag builds GEMM2 B-operand; no G LDS round-trip.
// Fragment-major LDS for W1/W2 (conflict-free lane-linear ds_read_b128).
// grid 256 = 16 chunks x 16 m-blocks; block 256 thr; wave owns m-64; 1 block/CU.
__global__ void __launch_bounds__(256, 1)
k_ffn2(const unsigned short* __restrict__ h2, const unsigned short* __restrict__ w1t,
       const unsigned short* __restrict__ w2t, const float* __restrict__ bf1,
       float* __restrict__ outp) {
  __shared__ __align__(16) unsigned short lA[2][16][512];  // W1 frags: F=sub*8+kk
  __shared__ __align__(16) unsigned short lB[2][16][512];  // W2 frags: F=et*4+ns
  int tid = threadIdx.x, w = tid >> 6, l = tid & 63, ln = l & 31, hi = l >> 5;
  int chunk = blockIdx.x & 15, mblk = blockIdx.x >> 4;
  int m0 = mblk * 256 + w * 64;

  // h2 B-operand fragments (resident): hb[mhalf][e-slice]
  bf16x8 hb[2][8];
#pragma unroll
  for (int mh = 0; mh < 2; mh++)
#pragma unroll
    for (int kk = 0; kk < 8; kk++)
      hb[mh][kk] = *reinterpret_cast<const bf16x8*>(
          h2 + (size_t)(m0 + mh * 32 + ln) * 128 + kk * 16 + hi * 8);

  f32x16 acc[4][2];
#pragma unroll
  for (int et = 0; et < 4; et++) { acc[et][0] = zero16(); acc[et][1] = zero16(); }

  uint4 stA[4], stB[4];
  // prologue: load + write tile 0
  {
    int nn = chunk * 4096;
#pragma unroll
    for (int p = 0; p < 4; p++) {
      int F = p * 4 + w;
      stA[p] = *reinterpret_cast<const uint4*>(
          w1t + (size_t)(nn + (F >> 3) * 32 + ln) * 128 + (F & 7) * 16 + hi * 8);
      stB[p] = *reinterpret_cast<const uint4*>(
          w2t + (size_t)((F >> 2) * 32 + ln) * 65536 + nn + (F & 3) * 16 + hi * 8);
    }
#pragma unroll
    for (int p = 0; p < 4; p++) {
      int F = p * 4 + w;
      *reinterpret_cast<uint4*>(&lA[0][F][l * 8]) = stA[p];
      *reinterpret_cast<uint4*>(&lB[0][F][l * 8]) = stB[p];
    }
  }
  __syncthreads();

  int cur = 0;
  for (int t = 0; t < 64; t++) {
    if (t < 63) {  // T14: issue next-tile loads early
      int nn = chunk * 4096 + (t + 1) * 64;
#pragma unroll
      for (int p = 0; p < 4; p++) {
        int F = p * 4 + w;
        stA[p] = *reinterpret_cast<const uint4*>(
            w1t + (size_t)(nn + (F >> 3) * 32 + ln) * 128 + (F & 7) * 16 + hi * 8);
        stB[p] = *reinterpret_cast<const uint4*>(
            w2t + (size_t)((F >> 2) * 32 + ln) * 65536 + nn + (F & 3) * 16 + hi * 8);
      }
    }
    int n0 = chunk * 4096 + t * 64;
    const unsigned short* A = &lA[cur][0][0];
    const unsigned short* B = &lB[cur][0][0];
#pragma unroll
    for (int sub = 0; sub < 2; sub++) {
      // GEMM1': Gt[n 32][m 32] per mhalf; K = e = 128
      f32x16 g0 = zero16(), g1 = zero16();
#pragma unroll
      for (int kk = 0; kk < 8; kk++) {
        bf16x8 a = *reinterpret_cast<const bf16x8*>(A + (sub * 8 + kk) * 512 + l * 8);
        g0 = MFMA(a, hb[0][kk], g0);
        g1 = MFMA(a, hb[1][kk], g1);
      }
      // bias + relu in-register (row r -> n-local (r&3)+8*(r>>2)+4*hi)
#pragma unroll
      for (int r = 0; r < 16; r++) {
        float bv = bf1[n0 + sub * 32 + (r & 3) + 8 * (r >> 2) + 4 * hi];
        g0[r] = fmaxf(g0[r] + bv, 0.f);
        g1[r] = fmaxf(g1[r] + bv, 0.f);
      }
      // GEMM2 B-operand fragments via cvt_pk+permlane
      bf16x8 pb00 = pfrag(g0[0], g0[1], g0[2], g0[3], g0[4], g0[5], g0[6], g0[7]);
      bf16x8 pb01 = pfrag(g0[8], g0[9], g0[10], g0[11], g0[12], g0[13], g0[14], g0[15]);
      bf16x8 pb10 = pfrag(g1[0], g1[1], g1[2], g1[3], g1[4], g1[5], g1[6], g1[7]);
      bf16x8 pb11 = pfrag(g1[8], g1[9], g1[10], g1[11], g1[12], g1[13], g1[14], g1[15]);
      // GEMM2': outT[e 128][m 64] += W2-as-A x Gt-as-B
#pragma unroll
      for (int et = 0; et < 4; et++) {
        bf16x8 wa0 = *reinterpret_cast<const bf16x8*>(B + (et * 4 + sub * 2 + 0) * 512 + l * 8);
        acc[et][0] = MFMA(wa0, pb00, acc[et][0]);
        acc[et][1] = MFMA(wa0, pb10, acc[et][1]);
        bf16x8 wa1 = *reinterpret_cast<const bf16x8*>(B + (et * 4 + sub * 2 + 1) * 512 + l * 8);
        acc[et][0] = MFMA(wa1, pb01, acc[et][0]);
        acc[et][1] = MFMA(wa1, pb11, acc[et][1]);
      }
    }
    if (t < 63) {  // write staged regs to the other buffer
#pragma unroll
      for (int p = 0; p < 4; p++) {
        int F = p * 4 + w;
        *reinterpret_cast<uint4*>(&lA[cur ^ 1][F][l * 8]) = stA[p];
        *reinterpret_cast<uint4*>(&lB[cur ^ 1][F][l * 8]) = stB[p];
      }
    }
    __syncthreads();
    cur ^= 1;
  }
  // epilogue: atomic accumulate (16 chunks into same outputs)
#pragma unroll
  for (int et = 0; et < 4; et++)
#pragma unroll
    for (int mh = 0; mh < 2; mh++)
#pragma unroll
      for (int r = 0; r < 16; r++) {
        int e = et * 32 + (r & 3) + 8 * (r >> 2) + 4 * hi;
        int m = m0 + mh * 32 + ln;
        atomicAdd(&outp[(size_t)m * 128 + e], acc[et][mh][r]);
      }
}

extern "C" void kernel_launch(void* const* d_in, const int* in_sizes, int n_in,
                              void* d_out, int out_size, void* d_ws, size_t ws_size,
                              hipStream_t stream) {
  (void)in_sizes; (void)n_in; (void)out_size; (void)ws_size;
  const float* x = (const float*)d_in[0];
  const float* Wk = (const float*)d_in[1];
  const float* Wq = (const float*)d_in[2];
  const float* Wv = (const float*)d_in[3];
  const float* Wo = (const float*)d_in[4];
  const float* bo = (const float*)d_in[5];
  const float* g1 = (const float*)d_in[6];
  const float* be1 = (const float*)d_in[7];
  const float* g2 = (const float*)d_in[8];
  const float* be2 = (const float*)d_in[9];
  const float* W1 = (const float*)d_in[10];
  const float* bf1 = (const float*)d_in[11];
  const float* W2 = (const float*)d_in[12];
  const float* bf2 = (const float*)d_in[13];
  float* outp = (float*)d_out;

  unsigned short* ws = (unsigned short*)d_ws;
  unsigned short* W1t = ws;                       // [65536][128] bf16
  unsigned short* W2t = ws + 8388608;             // [128][65536] bf16
  unsigned short* Wqkvt = ws + 16777216;          // [384][128]
  unsigned short* Wot = ws + 16826368;            // [128][128]
  unsigned short* h1 = ws + 16842752;             // [4096][128]
  unsigned short* h2 = ws + 17367040;             // [4096][128]
  unsigned short* qw = ws + 17891328;             // [16][2048][16]
  unsigned short* kw = ws + 18415616;
  unsigned short* vw = ws + 18939904;
  unsigned short* ow = ws + 19464192;             // [4096][128]
  float* x1 = (float*)(ws + 19988480);            // [4096][128] f32

  k_transpose<<<dim3(2048, 4), dim3(32, 8), 0, stream>>>(W1, W1t, 128, 65536);
  k_transpose<<<dim3(4, 2048), dim3(32, 8), 0, stream>>>(W2, W2t, 65536, 128);
  k_build_qkvo<<<256, 256, 0, stream>>>(Wq, Wk, Wv, Wo, Wqkvt, Wot);
  k_ln<<<1024, 256, 0, stream>>>(x, g1, be1, h1);
  k_gemm_qkv<<<dim3(32, 3), 256, 0, stream>>>(h1, Wqkvt, qw);
  k_attn2<<<dim3(16, 16), 256, 0, stream>>>(qw, kw, vw, ow);
  k_gemm_proj<<<32, 256, 0, stream>>>(ow, Wot, bo, x, bf2, x1, outp);
  k_ln<<<1024, 256, 0, stream>>>(x1, g2, be2, h2);
  k_ffn2<<<256, 256, 0, stream>>>(h2, W1t, W2t, bf1, outp);
}

// Round 6
// 611.486 us; speedup vs baseline: 1.2249x; 1.2249x over previous
//
#include <hip/hip_runtime.h>

typedef __bf16 bf16x8 __attribute__((ext_vector_type(8)));
typedef float f32x16 __attribute__((ext_vector_type(16)));

#define DEV static __device__ __forceinline__
#define MFMA(a, b, c) __builtin_amdgcn_mfma_f32_32x32x16_bf16((a), (b), (c), 0, 0, 0)

DEV unsigned short f2bf(float f) {
  unsigned u = __float_as_uint(f);
  unsigned r = u + 0x7fffu + ((u >> 16) & 1u);
  return (unsigned short)(r >> 16);
}
DEV float bflo(unsigned u) { return __uint_as_float(u << 16); }
DEV float bfhi(unsigned u) { return __uint_as_float(u & 0xffff0000u); }

DEV f32x16 zero16() {
  f32x16 z;
#pragma unroll
  for (int i = 0; i < 16; i++) z[i] = 0.f;
  return z;
}

// LDS fragment read helpers. Rows are XOR-swizzled by granule^(row&7).
DEV bf16x8 frag256(const unsigned short* lds, int rowbase, int l, int kk) {
  int row = rowbase + (l & 31);
  int gran = (kk << 1) + (l >> 5);
  return *reinterpret_cast<const bf16x8*>(&lds[row * 128 + ((gran ^ (row & 7)) << 3)]);
}

// ---------------- transpose + f32->bf16 convert: in[R][C] f32 -> out[C][R] bf16
__global__ void k_transpose(const float* __restrict__ in, unsigned short* __restrict__ out,
                            int R, int C) {
  __shared__ float t[32][33];
  int tx = threadIdx.x, ty = threadIdx.y;
  int c0 = blockIdx.x * 32, r0 = blockIdx.y * 32;
#pragma unroll
  for (int i = 0; i < 4; i++)
    t[ty + i * 8][tx] = in[(size_t)(r0 + ty + i * 8) * C + c0 + tx];
  __syncthreads();
#pragma unroll
  for (int i = 0; i < 4; i++)
    out[(size_t)(c0 + ty + i * 8) * R + r0 + tx] = f2bf(t[tx][ty + i * 8]);
}

// ---------------- build Wqkv_t [384][128] and Wo_t [128][128]
__global__ void k_build_qkvo(const float* __restrict__ Wq, const float* __restrict__ Wk,
                             const float* __restrict__ Wv, const float* __restrict__ Wo,
                             unsigned short* __restrict__ qkvt, unsigned short* __restrict__ wot) {
  int gid = blockIdx.x * 256 + threadIdx.x;
  if (gid < 49152) {
    int row = gid >> 7, e = gid & 127;
    int mi = row >> 7, c = row & 127, h = c >> 4, d = c & 15;
    const float* W = (mi == 0) ? Wq : (mi == 1) ? Wk : Wv;
    qkvt[gid] = f2bf(W[(h * 128 + e) * 16 + d]);
  } else {
    int id = gid - 49152;
    int n = id >> 7, k = id & 127;
    wot[id] = f2bf(Wo[k * 128 + n]);
  }
}

// ---------------- LayerNorm: one wave per 128-wide row, out bf16
__global__ void k_ln(const float* __restrict__ x, const float* __restrict__ g,
                     const float* __restrict__ b, unsigned short* __restrict__ out) {
  int row = blockIdx.x * 4 + (threadIdx.x >> 6);
  int l = threadIdx.x & 63;
  const float* xr = x + (size_t)row * 128;
  float x0 = xr[l * 2], x1v = xr[l * 2 + 1];
  float s = x0 + x1v;
#pragma unroll
  for (int m = 1; m < 64; m <<= 1) s += __shfl_xor(s, m, 64);
  float mu = s * 0.0078125f;
  float d0 = x0 - mu, d1 = x1v - mu;
  float ss = d0 * d0 + d1 * d1;
#pragma unroll
  for (int m = 1; m < 64; m <<= 1) ss += __shfl_xor(ss, m, 64);
  float inv = rsqrtf(ss * 0.0078125f + 1e-5f);
  float y0 = d0 * inv * g[l * 2] + b[l * 2];
  float y1 = d1 * inv * g[l * 2 + 1] + b[l * 2 + 1];
  unsigned u = ((unsigned)f2bf(y1) << 16) | (unsigned)f2bf(y0);
  *reinterpret_cast<unsigned*>(out + (size_t)row * 128 + l * 2) = u;
}

// ---------------- QKV projection
__global__ void k_gemm_qkv(const unsigned short* __restrict__ A, const unsigned short* __restrict__ Bt,
                           unsigned short* __restrict__ qkv) {
  __shared__ __align__(16) unsigned short As[128 * 128];
  __shared__ __align__(16) unsigned short Bs[128 * 128];
  int tid = threadIdx.x;
  int m0 = blockIdx.x * 128, n0 = blockIdx.y * 128;
  int sg = tid & 15, sr = tid >> 4;
#pragma unroll
  for (int i = 0; i < 8; i++) {
    int r = sr + i * 16;
    *reinterpret_cast<bf16x8*>(&As[r * 128 + ((sg ^ (r & 7)) << 3)]) =
        *reinterpret_cast<const bf16x8*>(A + (size_t)(m0 + r) * 128 + sg * 8);
    *reinterpret_cast<bf16x8*>(&Bs[r * 128 + ((sg ^ (r & 7)) << 3)]) =
        *reinterpret_cast<const bf16x8*>(Bt + (size_t)(n0 + r) * 128 + sg * 8);
  }
  __syncthreads();
  int l = tid & 63, w = tid >> 6, wmi = w >> 1, wni = w & 1;
  int ln = l & 31, hi = l >> 5;
  f32x16 acc[2][2];
  acc[0][0] = zero16(); acc[0][1] = zero16(); acc[1][0] = zero16(); acc[1][1] = zero16();
#pragma unroll
  for (int kk = 0; kk < 8; kk++) {
    bf16x8 a0 = frag256(As, wmi * 64, l, kk);
    bf16x8 a1 = frag256(As, wmi * 64 + 32, l, kk);
    bf16x8 b0 = frag256(Bs, wni * 64, l, kk);
    bf16x8 b1 = frag256(Bs, wni * 64 + 32, l, kk);
    acc[0][0] = MFMA(a0, b0, acc[0][0]);
    acc[0][1] = MFMA(a0, b1, acc[0][1]);
    acc[1][0] = MFMA(a1, b0, acc[1][0]);
    acc[1][1] = MFMA(a1, b1, acc[1][1]);
  }
  unsigned short* mat = qkv + (size_t)blockIdx.y * 524288;
#pragma unroll
  for (int im = 0; im < 2; im++)
#pragma unroll
    for (int in_ = 0; in_ < 2; in_++) {
      int c = wni * 64 + in_ * 32 + ln;
      int h = c >> 4, d = c & 15;
#pragma unroll
      for (int r = 0; r < 16; r++) {
        int m = m0 + wmi * 64 + im * 32 + (r & 3) + ((r >> 2) << 3) + (hi << 2);
        int bb = m >> 11, tt = m & 2047;
        mat[((size_t)((bb << 3) + h) * 2048 + tt) * 16 + d] = f2bf(acc[im][in_][r]);
      }
    }
}

// ---------------- MFMA flash attention (swapped QK^T, transposed PV) ----------------
DEV bf16x8 pfrag(float a0, float a1, float a2, float a3,
                 float a4, float a5, float a6, float a7) {
  unsigned c0, c1, c2, c3;
  asm("v_cvt_pk_bf16_f32 %0, %1, %2" : "=v"(c0) : "v"(a0), "v"(a1));
  asm("v_cvt_pk_bf16_f32 %0, %1, %2" : "=v"(c1) : "v"(a2), "v"(a3));
  asm("v_cvt_pk_bf16_f32 %0, %1, %2" : "=v"(c2) : "v"(a4), "v"(a5));
  asm("v_cvt_pk_bf16_f32 %0, %1, %2" : "=v"(c3) : "v"(a6), "v"(a7));
  asm("v_permlane32_swap_b32 %0, %1" : "+v"(c0), "+v"(c2));
  asm("v_permlane32_swap_b32 %0, %1" : "+v"(c1), "+v"(c3));
  int4 ri = make_int4((int)c0, (int)c1, (int)c2, (int)c3);
  return *reinterpret_cast<bf16x8*>(&ri);
}

__global__ void __launch_bounds__(256)
k_attn2(const unsigned short* __restrict__ qw, const unsigned short* __restrict__ kw,
        const unsigned short* __restrict__ vw, unsigned short* __restrict__ ow) {
  __shared__ __align__(16) unsigned short vt[2][16][72];  // V^T, padded rows (2-way banks)
  int tid = threadIdx.x;
  int qb = (int)gridDim.x - 1 - (int)blockIdx.x;  // heaviest q-tiles first
  int bh = blockIdx.y;
  int w = tid >> 6, l = tid & 63, ln = l & 31, hi = l >> 5;
  int q0 = qb * 128 + w * 32;
  int q = q0 + ln;
  const float SC = 0.08838834764831845f * 1.4426950408889634f;  // E^-0.5 * log2(e)
  const unsigned short* kbase = kw + (size_t)bh * 32768;
  const unsigned short* vbase = vw + (size_t)bh * 32768;
  // Q as B-operand: lane holds Q[q0+ln][hi*8 + i]
  bf16x8 qf = *reinterpret_cast<const bf16x8*>(qw + (size_t)bh * 32768 + (size_t)q * 16 + hi * 8);
  f32x16 acc = zero16();
  float mr = -1e30f, ls = 0.f;
  int ntiles = 2 * qb + 2;
  int skey = tid >> 1, sh = tid & 1;
  for (int st = 0; st < ntiles; st++) {
    int k0 = st * 64;
    int buf = st & 1;
    if (tid < 128) {  // stage V^T [16][64] for this tile
      const unsigned* vp = reinterpret_cast<const unsigned*>(vbase + (size_t)(k0 + skey) * 16 + sh * 8);
      unsigned u0 = vp[0], u1 = vp[1], u2 = vp[2], u3 = vp[3];
      int d0 = sh * 8;
      vt[buf][d0 + 0][skey] = (unsigned short)u0;
      vt[buf][d0 + 1][skey] = (unsigned short)(u0 >> 16);
      vt[buf][d0 + 2][skey] = (unsigned short)u1;
      vt[buf][d0 + 3][skey] = (unsigned short)(u1 >> 16);
      vt[buf][d0 + 4][skey] = (unsigned short)u2;
      vt[buf][d0 + 5][skey] = (unsigned short)(u2 >> 16);
      vt[buf][d0 + 6][skey] = (unsigned short)u3;
      vt[buf][d0 + 7][skey] = (unsigned short)(u3 >> 16);
    }
    __syncthreads();
    if (k0 > q0 + 31) continue;            // this wave's q-range done with these keys
    bool d1 = (k0 + 32 <= q0 + 31);        // need second 32-key subtile?
    f32x16 p0, p1;
    {
      bf16x8 ka = *reinterpret_cast<const bf16x8*>(kbase + (size_t)(k0 + ln) * 16 + hi * 8);
      p0 = MFMA(ka, qf, zero16());         // S^T: col=q, rows=keys
    }
    if (d1) {
      bf16x8 kb = *reinterpret_cast<const bf16x8*>(kbase + (size_t)(k0 + 32 + ln) * 16 + hi * 8);
      p1 = MFMA(kb, qf, zero16());
    }
    if (k0 + 31 > q0) {                    // subtile 1 overlaps diagonal: causal mask
#pragma unroll
      for (int r = 0; r < 16; r++) {
        int krow = (r & 3) + 8 * (r >> 2) + 4 * hi;
        if (k0 + krow > q) p0[r] = -1e30f;
      }
    }
    if (d1 && (k0 + 63 > q0)) {            // subtile 2 overlaps diagonal: causal mask
#pragma unroll
      for (int r = 0; r < 16; r++) {
        int krow = (r & 3) + 8 * (r >> 2) + 4 * hi;
        if (k0 + 32 + krow > q) p1[r] = -1e30f;
      }
    }
    // online softmax (raw scores; scale folded into exp2 arg)
    float tm = p0[0];
#pragma unroll
    for (int r = 1; r < 16; r++) tm = fmaxf(tm, p0[r]);
    if (d1) {
#pragma unroll
      for (int r = 0; r < 16; r++) tm = fmaxf(tm, p1[r]);
    }
    tm = fmaxf(tm, __shfl_xor(tm, 32, 64));
    if (tm > mr) {
      float corr = exp2f((mr - tm) * SC);
      ls *= corr;
#pragma unroll
      for (int r = 0; r < 8; r++) acc[r] *= corr;
      mr = tm;
    }
    float msc = mr * SC;
#pragma unroll
    for (int r = 0; r < 16; r++) {
      p0[r] = exp2f(fmaf(p0[r], SC, -msc));
      ls += p0[r];
    }
    if (d1) {
#pragma unroll
      for (int r = 0; r < 16; r++) {
        p1[r] = exp2f(fmaf(p1[r], SC, -msc));
        ls += p1[r];
      }
    }
    // PV: O^T += V^T * P^T  (A rows 16-31 duplicate d&15; D rows 16-31 unused)
    const unsigned short* vrow = &vt[buf][ln & 15][0];
    {
      bf16x8 pa = pfrag(p0[0], p0[1], p0[2], p0[3], p0[4], p0[5], p0[6], p0[7]);
      bf16x8 va = *reinterpret_cast<const bf16x8*>(vrow + hi * 8);
      acc = MFMA(va, pa, acc);
      pa = pfrag(p0[8], p0[9], p0[10], p0[11], p0[12], p0[13], p0[14], p0[15]);
      va = *reinterpret_cast<const bf16x8*>(vrow + 16 + hi * 8);
      acc = MFMA(va, pa, acc);
    }
    if (d1) {
      bf16x8 pa = pfrag(p1[0], p1[1], p1[2], p1[3], p1[4], p1[5], p1[6], p1[7]);
      bf16x8 va = *reinterpret_cast<const bf16x8*>(vrow + 32 + hi * 8);
      acc = MFMA(va, pa, acc);
      pa = pfrag(p1[8], p1[9], p1[10], p1[11], p1[12], p1[13], p1[14], p1[15]);
      va = *reinterpret_cast<const bf16x8*>(vrow + 48 + hi * 8);
      acc = MFMA(va, pa, acc);
    }
  }
  ls += __shfl_xor(ls, 32, 64);
  float rl = 1.0f / ls;
  int b_ = bh >> 3, h_ = bh & 7;
  unsigned short* op = ow + ((size_t)(b_ * 2048 + q)) * 128 + h_ * 16;
  int dbase = 4 * hi;  // acc rows r=0..7 -> d = (r&3) + 8*(r>>2) + 4*hi
  unsigned o0 = ((unsigned)f2bf(acc[1] * rl) << 16) | (unsigned)f2bf(acc[0] * rl);
  unsigned o1 = ((unsigned)f2bf(acc[3] * rl) << 16) | (unsigned)f2bf(acc[2] * rl);
  unsigned o2 = ((unsigned)f2bf(acc[5] * rl) << 16) | (unsigned)f2bf(acc[4] * rl);
  unsigned o3 = ((unsigned)f2bf(acc[7] * rl) << 16) | (unsigned)f2bf(acc[6] * rl);
  *reinterpret_cast<unsigned*>(op + dbase) = o0;
  *reinterpret_cast<unsigned*>(op + dbase + 2) = o1;
  *reinterpret_cast<unsigned*>(op + 8 + dbase) = o2;
  *reinterpret_cast<unsigned*>(op + 8 + dbase + 2) = o3;
}

// ---------------- output projection + residual
__global__ void k_gemm_proj(const unsigned short* __restrict__ A, const unsigned short* __restrict__ Bt,
                            const float* __restrict__ bo, const float* __restrict__ x,
                            const float* __restrict__ bf2, float* __restrict__ x1,
                            float* __restrict__ outp) {
  __shared__ __align__(16) unsigned short As[128 * 128];
  __shared__ __align__(16) unsigned short Bs[128 * 128];
  int tid = threadIdx.x;
  int m0 = blockIdx.x * 128;
  int sg = tid & 15, sr = tid >> 4;
#pragma unroll
  for (int i = 0; i < 8; i++) {
    int r = sr + i * 16;
    *reinterpret_cast<bf16x8*>(&As[r * 128 + ((sg ^ (r & 7)) << 3)]) =
        *reinterpret_cast<const bf16x8*>(A + (size_t)(m0 + r) * 128 + sg * 8);
    *reinterpret_cast<bf16x8*>(&Bs[r * 128 + ((sg ^ (r & 7)) << 3)]) =
        *reinterpret_cast<const bf16x8*>(Bt + (size_t)r * 128 + sg * 8);
  }
  __syncthreads();
  int l = tid & 63, w = tid >> 6, wmi = w >> 1, wni = w & 1;
  int ln = l & 31, hi = l >> 5;
  f32x16 acc[2][2];
  acc[0][0] = zero16(); acc[0][1] = zero16(); acc[1][0] = zero16(); acc[1][1] = zero16();
#pragma unroll
  for (int kk = 0; kk < 8; kk++) {
    bf16x8 a0 = frag256(As, wmi * 64, l, kk);
    bf16x8 a1 = frag256(As, wmi * 64 + 32, l, kk);
    bf16x8 b0 = frag256(Bs, wni * 64, l, kk);
    bf16x8 b1 = frag256(Bs, wni * 64 + 32, l, kk);
    acc[0][0] = MFMA(a0, b0, acc[0][0]);
    acc[0][1] = MFMA(a0, b1, acc[0][1]);
    acc[1][0] = MFMA(a1, b0, acc[1][0]);
    acc[1][1] = MFMA(a1, b1, acc[1][1]);
  }
#pragma unroll
  for (int im = 0; im < 2; im++)
#pragma unroll
    for (int in_ = 0; in_ < 2; in_++) {
      int n = wni * 64 + in_ * 32 + ln;
      float bon = bo[n], b2n = bf2[n];
#pragma unroll
      for (int r = 0; r < 16; r++) {
        int m = m0 + wmi * 64 + im * 32 + (r & 3) + ((r >> 2) << 3) + (hi << 2);
        float v = acc[im][in_][r] + bon;
        float xv = x[(size_t)m * 128 + n] + v;
        x1[(size_t)m * 128 + n] = xv;
        outp[(size_t)m * 128 + n] = xv + b2n;
      }
    }
}

// ---------------- fused FFN v3: out += relu(h2@W1+bf1)@W2
// GEMM2 operand-swapped (pb as A, W2-frag as B) -> out[m][e] with lane = e
// -> coalesced epilogue. Grid 512 = 16 chunks x 32 m-blocks (M=128/block,
// wave owns m-32); 2 blocks/CU, 2 waves/SIMD. If `part` != null, write
// per-chunk partials (no atomics) and k_reduce sums; else coalesced atomics.
__global__ void __launch_bounds__(256, 2)
k_ffn3(const unsigned short* __restrict__ h2, const unsigned short* __restrict__ w1t,
       const unsigned short* __restrict__ w2t, const float* __restrict__ bf1,
       float* __restrict__ outp, float* __restrict__ part) {
  __shared__ __align__(16) unsigned short lA[2][16][512];  // W1 frags: F=sub*8+kk
  __shared__ __align__(16) unsigned short lB[2][16][512];  // W2 frags: F=et*4+ns
  int tid = threadIdx.x, w = tid >> 6, l = tid & 63, ln = l & 31, hi = l >> 5;
  int chunk = blockIdx.x & 15, mblk = blockIdx.x >> 4;
  int m0 = mblk * 128 + w * 32;

  // h2 B-operand fragments for GEMM1 (resident): lane ln = m-local
  bf16x8 hb[8];
#pragma unroll
  for (int kk = 0; kk < 8; kk++)
    hb[kk] = *reinterpret_cast<const bf16x8*>(
        h2 + (size_t)(m0 + ln) * 128 + kk * 16 + hi * 8);

  f32x16 acc[4];
#pragma unroll
  for (int et = 0; et < 4; et++) acc[et] = zero16();

  uint4 stA[4], stB[4];
  // prologue: load + write tile 0
  {
    int nn = chunk * 4096;
#pragma unroll
    for (int p = 0; p < 4; p++) {
      int F = p * 4 + w;
      stA[p] = *reinterpret_cast<const uint4*>(
          w1t + (size_t)(nn + (F >> 3) * 32 + ln) * 128 + (F & 7) * 16 + hi * 8);
      stB[p] = *reinterpret_cast<const uint4*>(
          w2t + (size_t)((F >> 2) * 32 + ln) * 65536 + nn + (F & 3) * 16 + hi * 8);
    }
#pragma unroll
    for (int p = 0; p < 4; p++) {
      int F = p * 4 + w;
      *reinterpret_cast<uint4*>(&lA[0][F][l * 8]) = stA[p];
      *reinterpret_cast<uint4*>(&lB[0][F][l * 8]) = stB[p];
    }
  }
  __syncthreads();

  int cur = 0;
  for (int t = 0; t < 64; t++) {
    if (t < 63) {  // T14: issue next-tile loads early
      int nn = chunk * 4096 + (t + 1) * 64;
#pragma unroll
      for (int p = 0; p < 4; p++) {
        int F = p * 4 + w;
        stA[p] = *reinterpret_cast<const uint4*>(
            w1t + (size_t)(nn + (F >> 3) * 32 + ln) * 128 + (F & 7) * 16 + hi * 8);
        stB[p] = *reinterpret_cast<const uint4*>(
            w2t + (size_t)((F >> 2) * 32 + ln) * 65536 + nn + (F & 3) * 16 + hi * 8);
      }
    }
    int n0 = chunk * 4096 + t * 64;
    const unsigned short* A = &lA[cur][0][0];
    const unsigned short* B = &lB[cur][0][0];
#pragma unroll
    for (int sub = 0; sub < 2; sub++) {
      // GEMM1': Gt[n 32][m 32] ; K = e = 128
      f32x16 g0 = zero16();
#pragma unroll
      for (int kk = 0; kk < 8; kk++) {
        bf16x8 a = *reinterpret_cast<const bf16x8*>(A + (sub * 8 + kk) * 512 + l * 8);
        g0 = MFMA(a, hb[kk], g0);
      }
      // bias + relu in-register (row r -> n-local (r&3)+8*(r>>2)+4*hi)
#pragma unroll
      for (int r = 0; r < 16; r++) {
        float bv = bf1[n0 + sub * 32 + (r & 3) + 8 * (r >> 2) + 4 * hi];
        g0[r] = fmaxf(g0[r] + bv, 0.f);
      }
      // H-fragments (lane = m-local, k = n-slice) via cvt_pk+permlane
      bf16x8 pb0 = pfrag(g0[0], g0[1], g0[2], g0[3], g0[4], g0[5], g0[6], g0[7]);
      bf16x8 pb1 = pfrag(g0[8], g0[9], g0[10], g0[11], g0[12], g0[13], g0[14], g0[15]);
      // GEMM2: out[m 32][e 128] += H-as-A x W2-as-B  (operand order = coalesced C)
#pragma unroll
      for (int et = 0; et < 4; et++) {
        bf16x8 wa0 = *reinterpret_cast<const bf16x8*>(B + (et * 4 + sub * 2 + 0) * 512 + l * 8);
        acc[et] = MFMA(pb0, wa0, acc[et]);
        bf16x8 wa1 = *reinterpret_cast<const bf16x8*>(B + (et * 4 + sub * 2 + 1) * 512 + l * 8);
        acc[et] = MFMA(pb1, wa1, acc[et]);
      }
    }
    if (t < 63) {  // write staged regs to the other buffer
#pragma unroll
      for (int p = 0; p < 4; p++) {
        int F = p * 4 + w;
        *reinterpret_cast<uint4*>(&lA[cur ^ 1][F][l * 8]) = stA[p];
        *reinterpret_cast<uint4*>(&lB[cur ^ 1][F][l * 8]) = stB[p];
      }
    }
    __syncthreads();
    cur ^= 1;
  }
  // epilogue: lane ln = e (consecutive) -> coalesced stores/atomics
  if (part) {
    float* pbase = part + (size_t)chunk * 524288;
#pragma unroll
    for (int et = 0; et < 4; et++)
#pragma unroll
      for (int r = 0; r < 16; r++) {
        int m = m0 + (r & 3) + 8 * (r >> 2) + 4 * hi;
        pbase[(size_t)m * 128 + et * 32 + ln] = acc[et][r];
      }
  } else {
#pragma unroll
    for (int et = 0; et < 4; et++)
#pragma unroll
      for (int r = 0; r < 16; r++) {
        int m = m0 + (r & 3) + 8 * (r >> 2) + 4 * hi;
        atomicAdd(&outp[(size_t)m * 128 + et * 32 + ln], acc[et][r]);
      }
  }
}

// ---------------- sum 16 FFN partials into outp
__global__ void k_reduce(const float* __restrict__ part, float* __restrict__ outp) {
  int i = (blockIdx.x * 256 + threadIdx.x) * 4;
  float4 s = *reinterpret_cast<const float4*>(outp + i);
#pragma unroll
  for (int c = 0; c < 16; c++) {
    float4 p = *reinterpret_cast<const float4*>(part + (size_t)c * 524288 + i);
    s.x += p.x; s.y += p.y; s.z += p.z; s.w += p.w;
  }
  *reinterpret_cast<float4*>(outp + i) = s;
}

extern "C" void kernel_launch(void* const* d_in, const int* in_sizes, int n_in,
                              void* d_out, int out_size, void* d_ws, size_t ws_size,
                              hipStream_t stream) {
  (void)in_sizes; (void)n_in; (void)out_size;
  const float* x = (const float*)d_in[0];
  const float* Wk = (const float*)d_in[1];
  const float* Wq = (const float*)d_in[2];
  const float* Wv = (const float*)d_in[3];
  const float* Wo = (const float*)d_in[4];
  const float* bo = (const float*)d_in[5];
  const float* g1 = (const float*)d_in[6];
  const float* be1 = (const float*)d_in[7];
  const float* g2 = (const float*)d_in[8];
  const float* be2 = (const float*)d_in[9];
  const float* W1 = (const float*)d_in[10];
  const float* bf1 = (const float*)d_in[11];
  const float* W2 = (const float*)d_in[12];
  const float* bf2 = (const float*)d_in[13];
  float* outp = (float*)d_out;

  unsigned short* ws = (unsigned short*)d_ws;
  unsigned short* W1t = ws;                       // [65536][128] bf16
  unsigned short* W2t = ws + 8388608;             // [128][65536] bf16
  unsigned short* Wqkvt = ws + 16777216;          // [384][128]
  unsigned short* Wot = ws + 16826368;            // [128][128]
  unsigned short* h1 = ws + 16842752;             // [4096][128]
  unsigned short* h2 = ws + 17367040;             // [4096][128]
  unsigned short* qw = ws + 17891328;             // [16][2048][16]
  unsigned short* kw = ws + 18415616;
  unsigned short* vw = ws + 18939904;
  unsigned short* ow = ws + 19464192;             // [4096][128]
  float* x1 = (float*)(ws + 19988480);            // [4096][128] f32
  // partials after x1: byte offset 42,074,112 ; 16 x 2 MB = 33,554,432 bytes
  bool use_part = ws_size >= (size_t)75628544;
  float* part = use_part ? (float*)(ws + 21037056) : (float*)nullptr;

  k_transpose<<<dim3(2048, 4), dim3(32, 8), 0, stream>>>(W1, W1t, 128, 65536);
  k_transpose<<<dim3(4, 2048), dim3(32, 8), 0, stream>>>(W2, W2t, 65536, 128);
  k_build_qkvo<<<256, 256, 0, stream>>>(Wq, Wk, Wv, Wo, Wqkvt, Wot);
  k_ln<<<1024, 256, 0, stream>>>(x, g1, be1, h1);
  k_gemm_qkv<<<dim3(32, 3), 256, 0, stream>>>(h1, Wqkvt, qw);
  k_attn2<<<dim3(16, 16), 256, 0, stream>>>(qw, kw, vw, ow);
  k_gemm_proj<<<32, 256, 0, stream>>>(ow, Wot, bo, x, bf2, x1, outp);
  k_ln<<<1024, 256, 0, stream>>>(x1, g2, be2, h2);
  k_ffn3<<<512, 256, 0, stream>>>(h2, W1t, W2t, bf1, outp, part);
  if (use_part) k_reduce<<<512, 256, 0, stream>>>(part, outp);
}

// Round 7
// 462.668 us; speedup vs baseline: 1.6189x; 1.3216x over previous
//
#include <hip/hip_runtime.h>

typedef __bf16 bf16x8 __attribute__((ext_vector_type(8)));
typedef float f32x16 __attribute__((ext_vector_type(16)));

#define DEV static __device__ __forceinline__
#define MFMA(a, b, c) __builtin_amdgcn_mfma_f32_32x32x16_bf16((a), (b), (c), 0, 0, 0)

DEV unsigned short f2bf(float f) {
  unsigned u = __float_as_uint(f);
  unsigned r = u + 0x7fffu + ((u >> 16) & 1u);
  return (unsigned short)(r >> 16);
}
DEV float bflo(unsigned u) { return __uint_as_float(u << 16); }
DEV float bfhi(unsigned u) { return __uint_as_float(u & 0xffff0000u); }

DEV f32x16 zero16() {
  f32x16 z;
#pragma unroll
  for (int i = 0; i < 16; i++) z[i] = 0.f;
  return z;
}

// LDS fragment read helpers. Rows are XOR-swizzled by granule^(row&7).
DEV bf16x8 frag256(const unsigned short* lds, int rowbase, int l, int kk) {
  int row = rowbase + (l & 31);
  int gran = (kk << 1) + (l >> 5);
  return *reinterpret_cast<const bf16x8*>(&lds[row * 128 + ((gran ^ (row & 7)) << 3)]);
}

// ---------------- transpose + f32->bf16 convert: in[R][C] f32 -> out[C][R] bf16
__global__ void k_transpose(const float* __restrict__ in, unsigned short* __restrict__ out,
                            int R, int C) {
  __shared__ float t[32][33];
  int tx = threadIdx.x, ty = threadIdx.y;
  int c0 = blockIdx.x * 32, r0 = blockIdx.y * 32;
#pragma unroll
  for (int i = 0; i < 4; i++)
    t[ty + i * 8][tx] = in[(size_t)(r0 + ty + i * 8) * C + c0 + tx];
  __syncthreads();
#pragma unroll
  for (int i = 0; i < 4; i++)
    out[(size_t)(c0 + ty + i * 8) * R + r0 + tx] = f2bf(t[tx][ty + i * 8]);
}

// ---------------- build Wqkv_t [384][128] and Wo_t [128][128]
__global__ void k_build_qkvo(const float* __restrict__ Wq, const float* __restrict__ Wk,
                             const float* __restrict__ Wv, const float* __restrict__ Wo,
                             unsigned short* __restrict__ qkvt, unsigned short* __restrict__ wot) {
  int gid = blockIdx.x * 256 + threadIdx.x;
  if (gid < 49152) {
    int row = gid >> 7, e = gid & 127;
    int mi = row >> 7, c = row & 127, h = c >> 4, d = c & 15;
    const float* W = (mi == 0) ? Wq : (mi == 1) ? Wk : Wv;
    qkvt[gid] = f2bf(W[(h * 128 + e) * 16 + d]);
  } else {
    int id = gid - 49152;
    int n = id >> 7, k = id & 127;
    wot[id] = f2bf(Wo[k * 128 + n]);
  }
}

// ---------------- LayerNorm: one wave per 128-wide row, out bf16
__global__ void k_ln(const float* __restrict__ x, const float* __restrict__ g,
                     const float* __restrict__ b, unsigned short* __restrict__ out) {
  int row = blockIdx.x * 4 + (threadIdx.x >> 6);
  int l = threadIdx.x & 63;
  const float* xr = x + (size_t)row * 128;
  float x0 = xr[l * 2], x1v = xr[l * 2 + 1];
  float s = x0 + x1v;
#pragma unroll
  for (int m = 1; m < 64; m <<= 1) s += __shfl_xor(s, m, 64);
  float mu = s * 0.0078125f;
  float d0 = x0 - mu, d1 = x1v - mu;
  float ss = d0 * d0 + d1 * d1;
#pragma unroll
  for (int m = 1; m < 64; m <<= 1) ss += __shfl_xor(ss, m, 64);
  float inv = rsqrtf(ss * 0.0078125f + 1e-5f);
  float y0 = d0 * inv * g[l * 2] + b[l * 2];
  float y1 = d1 * inv * g[l * 2 + 1] + b[l * 2 + 1];
  unsigned u = ((unsigned)f2bf(y1) << 16) | (unsigned)f2bf(y0);
  *reinterpret_cast<unsigned*>(out + (size_t)row * 128 + l * 2) = u;
}

// ---------------- QKV projection
__global__ void k_gemm_qkv(const unsigned short* __restrict__ A, const unsigned short* __restrict__ Bt,
                           unsigned short* __restrict__ qkv) {
  __shared__ __align__(16) unsigned short As[128 * 128];
  __shared__ __align__(16) unsigned short Bs[128 * 128];
  int tid = threadIdx.x;
  int m0 = blockIdx.x * 128, n0 = blockIdx.y * 128;
  int sg = tid & 15, sr = tid >> 4;
#pragma unroll
  for (int i = 0; i < 8; i++) {
    int r = sr + i * 16;
    *reinterpret_cast<bf16x8*>(&As[r * 128 + ((sg ^ (r & 7)) << 3)]) =
        *reinterpret_cast<const bf16x8*>(A + (size_t)(m0 + r) * 128 + sg * 8);
    *reinterpret_cast<bf16x8*>(&Bs[r * 128 + ((sg ^ (r & 7)) << 3)]) =
        *reinterpret_cast<const bf16x8*>(Bt + (size_t)(n0 + r) * 128 + sg * 8);
  }
  __syncthreads();
  int l = tid & 63, w = tid >> 6, wmi = w >> 1, wni = w & 1;
  int ln = l & 31, hi = l >> 5;
  f32x16 acc[2][2];
  acc[0][0] = zero16(); acc[0][1] = zero16(); acc[1][0] = zero16(); acc[1][1] = zero16();
#pragma unroll
  for (int kk = 0; kk < 8; kk++) {
    bf16x8 a0 = frag256(As, wmi * 64, l, kk);
    bf16x8 a1 = frag256(As, wmi * 64 + 32, l, kk);
    bf16x8 b0 = frag256(Bs, wni * 64, l, kk);
    bf16x8 b1 = frag256(Bs, wni * 64 + 32, l, kk);
    acc[0][0] = MFMA(a0, b0, acc[0][0]);
    acc[0][1] = MFMA(a0, b1, acc[0][1]);
    acc[1][0] = MFMA(a1, b0, acc[1][0]);
    acc[1][1] = MFMA(a1, b1, acc[1][1]);
  }
  unsigned short* mat = qkv + (size_t)blockIdx.y * 524288;
#pragma unroll
  for (int im = 0; im < 2; im++)
#pragma unroll
    for (int in_ = 0; in_ < 2; in_++) {
      int c = wni * 64 + in_ * 32 + ln;
      int h = c >> 4, d = c & 15;
#pragma unroll
      for (int r = 0; r < 16; r++) {
        int m = m0 + wmi * 64 + im * 32 + (r & 3) + ((r >> 2) << 3) + (hi << 2);
        int bb = m >> 11, tt = m & 2047;
        mat[((size_t)((bb << 3) + h) * 2048 + tt) * 16 + d] = f2bf(acc[im][in_][r]);
      }
    }
}

// ---------------- MFMA flash attention (swapped QK^T, transposed PV) ----------------
DEV bf16x8 pfrag(float a0, float a1, float a2, float a3,
                 float a4, float a5, float a6, float a7) {
  unsigned c0, c1, c2, c3;
  asm("v_cvt_pk_bf16_f32 %0, %1, %2" : "=v"(c0) : "v"(a0), "v"(a1));
  asm("v_cvt_pk_bf16_f32 %0, %1, %2" : "=v"(c1) : "v"(a2), "v"(a3));
  asm("v_cvt_pk_bf16_f32 %0, %1, %2" : "=v"(c2) : "v"(a4), "v"(a5));
  asm("v_cvt_pk_bf16_f32 %0, %1, %2" : "=v"(c3) : "v"(a6), "v"(a7));
  asm("v_permlane32_swap_b32 %0, %1" : "+v"(c0), "+v"(c2));
  asm("v_permlane32_swap_b32 %0, %1" : "+v"(c1), "+v"(c3));
  int4 ri = make_int4((int)c0, (int)c1, (int)c2, (int)c3);
  return *reinterpret_cast<bf16x8*>(&ri);
}

__global__ void __launch_bounds__(256)
k_attn2(const unsigned short* __restrict__ qw, const unsigned short* __restrict__ kw,
        const unsigned short* __restrict__ vw, unsigned short* __restrict__ ow) {
  __shared__ __align__(16) unsigned short vt[2][16][72];  // V^T, padded rows (2-way banks)
  int tid = threadIdx.x;
  int qb = (int)gridDim.x - 1 - (int)blockIdx.x;  // heaviest q-tiles first
  int bh = blockIdx.y;
  int w = tid >> 6, l = tid & 63, ln = l & 31, hi = l >> 5;
  int q0 = qb * 128 + w * 32;
  int q = q0 + ln;
  const float SC = 0.08838834764831845f * 1.4426950408889634f;  // E^-0.5 * log2(e)
  const unsigned short* kbase = kw + (size_t)bh * 32768;
  const unsigned short* vbase = vw + (size_t)bh * 32768;
  // Q as B-operand: lane holds Q[q0+ln][hi*8 + i]
  bf16x8 qf = *reinterpret_cast<const bf16x8*>(qw + (size_t)bh * 32768 + (size_t)q * 16 + hi * 8);
  f32x16 acc = zero16();
  float mr = -1e30f, ls = 0.f;
  int ntiles = 2 * qb + 2;
  int skey = tid >> 1, sh = tid & 1;
  for (int st = 0; st < ntiles; st++) {
    int k0 = st * 64;
    int buf = st & 1;
    if (tid < 128) {  // stage V^T [16][64] for this tile
      const unsigned* vp = reinterpret_cast<const unsigned*>(vbase + (size_t)(k0 + skey) * 16 + sh * 8);
      unsigned u0 = vp[0], u1 = vp[1], u2 = vp[2], u3 = vp[3];
      int d0 = sh * 8;
      vt[buf][d0 + 0][skey] = (unsigned short)u0;
      vt[buf][d0 + 1][skey] = (unsigned short)(u0 >> 16);
      vt[buf][d0 + 2][skey] = (unsigned short)u1;
      vt[buf][d0 + 3][skey] = (unsigned short)(u1 >> 16);
      vt[buf][d0 + 4][skey] = (unsigned short)u2;
      vt[buf][d0 + 5][skey] = (unsigned short)(u2 >> 16);
      vt[buf][d0 + 6][skey] = (unsigned short)u3;
      vt[buf][d0 + 7][skey] = (unsigned short)(u3 >> 16);
    }
    __syncthreads();
    if (k0 > q0 + 31) continue;            // this wave's q-range done with these keys
    bool d1 = (k0 + 32 <= q0 + 31);        // need second 32-key subtile?
    f32x16 p0, p1;
    {
      bf16x8 ka = *reinterpret_cast<const bf16x8*>(kbase + (size_t)(k0 + ln) * 16 + hi * 8);
      p0 = MFMA(ka, qf, zero16());         // S^T: col=q, rows=keys
    }
    if (d1) {
      bf16x8 kb = *reinterpret_cast<const bf16x8*>(kbase + (size_t)(k0 + 32 + ln) * 16 + hi * 8);
      p1 = MFMA(kb, qf, zero16());
    }
    if (k0 + 31 > q0) {                    // subtile 1 overlaps diagonal: causal mask
#pragma unroll
      for (int r = 0; r < 16; r++) {
        int krow = (r & 3) + 8 * (r >> 2) + 4 * hi;
        if (k0 + krow > q) p0[r] = -1e30f;
      }
    }
    if (d1 && (k0 + 63 > q0)) {            // subtile 2 overlaps diagonal: causal mask
#pragma unroll
      for (int r = 0; r < 16; r++) {
        int krow = (r & 3) + 8 * (r >> 2) + 4 * hi;
        if (k0 + 32 + krow > q) p1[r] = -1e30f;
      }
    }
    // online softmax (raw scores; scale folded into exp2 arg)
    float tm = p0[0];
#pragma unroll
    for (int r = 1; r < 16; r++) tm = fmaxf(tm, p0[r]);
    if (d1) {
#pragma unroll
      for (int r = 0; r < 16; r++) tm = fmaxf(tm, p1[r]);
    }
    tm = fmaxf(tm, __shfl_xor(tm, 32, 64));
    if (tm > mr) {
      float corr = exp2f((mr - tm) * SC);
      ls *= corr;
#pragma unroll
      for (int r = 0; r < 8; r++) acc[r] *= corr;
      mr = tm;
    }
    float msc = mr * SC;
#pragma unroll
    for (int r = 0; r < 16; r++) {
      p0[r] = exp2f(fmaf(p0[r], SC, -msc));
      ls += p0[r];
    }
    if (d1) {
#pragma unroll
      for (int r = 0; r < 16; r++) {
        p1[r] = exp2f(fmaf(p1[r], SC, -msc));
        ls += p1[r];
      }
    }
    // PV: O^T += V^T * P^T  (A rows 16-31 duplicate d&15; D rows 16-31 unused)
    const unsigned short* vrow = &vt[buf][ln & 15][0];
    {
      bf16x8 pa = pfrag(p0[0], p0[1], p0[2], p0[3], p0[4], p0[5], p0[6], p0[7]);
      bf16x8 va = *reinterpret_cast<const bf16x8*>(vrow + hi * 8);
      acc = MFMA(va, pa, acc);
      pa = pfrag(p0[8], p0[9], p0[10], p0[11], p0[12], p0[13], p0[14], p0[15]);
      va = *reinterpret_cast<const bf16x8*>(vrow + 16 + hi * 8);
      acc = MFMA(va, pa, acc);
    }
    if (d1) {
      bf16x8 pa = pfrag(p1[0], p1[1], p1[2], p1[3], p1[4], p1[5], p1[6], p1[7]);
      bf16x8 va = *reinterpret_cast<const bf16x8*>(vrow + 32 + hi * 8);
      acc = MFMA(va, pa, acc);
      pa = pfrag(p1[8], p1[9], p1[10], p1[11], p1[12], p1[13], p1[14], p1[15]);
      va = *reinterpret_cast<const bf16x8*>(vrow + 48 + hi * 8);
      acc = MFMA(va, pa, acc);
    }
  }
  ls += __shfl_xor(ls, 32, 64);
  float rl = 1.0f / ls;
  int b_ = bh >> 3, h_ = bh & 7;
  unsigned short* op = ow + ((size_t)(b_ * 2048 + q)) * 128 + h_ * 16;
  int dbase = 4 * hi;  // acc rows r=0..7 -> d = (r&3) + 8*(r>>2) + 4*hi
  unsigned o0 = ((unsigned)f2bf(acc[1] * rl) << 16) | (unsigned)f2bf(acc[0] * rl);
  unsigned o1 = ((unsigned)f2bf(acc[3] * rl) << 16) | (unsigned)f2bf(acc[2] * rl);
  unsigned o2 = ((unsigned)f2bf(acc[5] * rl) << 16) | (unsigned)f2bf(acc[4] * rl);
  unsigned o3 = ((unsigned)f2bf(acc[7] * rl) << 16) | (unsigned)f2bf(acc[6] * rl);
  *reinterpret_cast<unsigned*>(op + dbase) = o0;
  *reinterpret_cast<unsigned*>(op + dbase + 2) = o1;
  *reinterpret_cast<unsigned*>(op + 8 + dbase) = o2;
  *reinterpret_cast<unsigned*>(op + 8 + dbase + 2) = o3;
}

// ---------------- output projection + residual
__global__ void k_gemm_proj(const unsigned short* __restrict__ A, const unsigned short* __restrict__ Bt,
                            const float* __restrict__ bo, const float* __restrict__ x,
                            const float* __restrict__ bf2, float* __restrict__ x1,
                            float* __restrict__ outp) {
  __shared__ __align__(16) unsigned short As[128 * 128];
  __shared__ __align__(16) unsigned short Bs[128 * 128];
  int tid = threadIdx.x;
  int m0 = blockIdx.x * 128;
  int sg = tid & 15, sr = tid >> 4;
#pragma unroll
  for (int i = 0; i < 8; i++) {
    int r = sr + i * 16;
    *reinterpret_cast<bf16x8*>(&As[r * 128 + ((sg ^ (r & 7)) << 3)]) =
        *reinterpret_cast<const bf16x8*>(A + (size_t)(m0 + r) * 128 + sg * 8);
    *reinterpret_cast<bf16x8*>(&Bs[r * 128 + ((sg ^ (r & 7)) << 3)]) =
        *reinterpret_cast<const bf16x8*>(Bt + (size_t)r * 128 + sg * 8);
  }
  __syncthreads();
  int l = tid & 63, w = tid >> 6, wmi = w >> 1, wni = w & 1;
  int ln = l & 31, hi = l >> 5;
  f32x16 acc[2][2];
  acc[0][0] = zero16(); acc[0][1] = zero16(); acc[1][0] = zero16(); acc[1][1] = zero16();
#pragma unroll
  for (int kk = 0; kk < 8; kk++) {
    bf16x8 a0 = frag256(As, wmi * 64, l, kk);
    bf16x8 a1 = frag256(As, wmi * 64 + 32, l, kk);
    bf16x8 b0 = frag256(Bs, wni * 64, l, kk);
    bf16x8 b1 = frag256(Bs, wni * 64 + 32, l, kk);
    acc[0][0] = MFMA(a0, b0, acc[0][0]);
    acc[0][1] = MFMA(a0, b1, acc[0][1]);
    acc[1][0] = MFMA(a1, b0, acc[1][0]);
    acc[1][1] = MFMA(a1, b1, acc[1][1]);
  }
#pragma unroll
  for (int im = 0; im < 2; im++)
#pragma unroll
    for (int in_ = 0; in_ < 2; in_++) {
      int n = wni * 64 + in_ * 32 + ln;
      float bon = bo[n], b2n = bf2[n];
#pragma unroll
      for (int r = 0; r < 16; r++) {
        int m = m0 + wmi * 64 + im * 32 + (r & 3) + ((r >> 2) << 3) + (hi << 2);
        float v = acc[im][in_][r] + bon;
        float xv = x[(size_t)m * 128 + n] + v;
        x1[(size_t)m * 128 + n] = xv;
        outp[(size_t)m * 128 + n] = xv + b2n;
      }
    }
}

// ---------------- fused FFN v4: out += relu(h2@W1+bf1)@W2
// v3 fragment algebra (proven correct) + nm=2 m-tiles/wave so every LDS
// fragment read feeds 2 MFMAs (32 reads : 64 MFMAs per wave-iter).
// Block = 4 waves, M_block=256; grid 512 = 32 chunks (width 2048, 32 iters)
// x 16 m-blocks; chunk = bid&31 keeps same-chunk blocks on one XCD (4MB L2).
// Double-buffered W tiles, 1 barrier/iter, staged regs written mid-iter.
__global__ void __launch_bounds__(256, 2)
k_ffn4(const unsigned short* __restrict__ h2, const unsigned short* __restrict__ w1t,
       const unsigned short* __restrict__ w2t, const float* __restrict__ bf1,
       float* __restrict__ outp) {
  __shared__ __align__(16) unsigned short lA[2][16][512];  // W1 frags: F=sub*8+kk
  __shared__ __align__(16) unsigned short lB[2][16][512];  // W2 frags: F=et*4+sub*2+ks
  int tid = threadIdx.x, w = tid >> 6, l = tid & 63, ln = l & 31, hi = l >> 5;
  int chunk = blockIdx.x & 31, mblk = blockIdx.x >> 5;
  int m0 = mblk * 256 + w * 64;

  // h2 B-operand fragments for GEMM1 (resident): hb[mh][e-slice]
  bf16x8 hb[2][8];
#pragma unroll
  for (int mh = 0; mh < 2; mh++)
#pragma unroll
    for (int kk = 0; kk < 8; kk++)
      hb[mh][kk] = *reinterpret_cast<const bf16x8*>(
          h2 + (size_t)(m0 + mh * 32 + ln) * 128 + kk * 16 + hi * 8);

  f32x16 acc[4][2];
#pragma unroll
  for (int et = 0; et < 4; et++) { acc[et][0] = zero16(); acc[et][1] = zero16(); }

  uint4 stA[4], stB[4];
  // prologue: load + write tile 0
  {
    int nn = chunk * 2048;
#pragma unroll
    for (int p = 0; p < 4; p++) {
      int F = p * 4 + w;
      stA[p] = *reinterpret_cast<const uint4*>(
          w1t + (size_t)(nn + (F >> 3) * 32 + ln) * 128 + (F & 7) * 16 + hi * 8);
      stB[p] = *reinterpret_cast<const uint4*>(
          w2t + (size_t)((F >> 2) * 32 + ln) * 65536 + nn + (F & 3) * 16 + hi * 8);
    }
#pragma unroll
    for (int p = 0; p < 4; p++) {
      int F = p * 4 + w;
      *reinterpret_cast<uint4*>(&lA[0][F][l * 8]) = stA[p];
      *reinterpret_cast<uint4*>(&lB[0][F][l * 8]) = stB[p];
    }
  }
  __syncthreads();

  int cur = 0;
  for (int t = 0; t < 32; t++) {
    if (t < 31) {  // T14: issue next-tile loads early
      int nn = chunk * 2048 + (t + 1) * 64;
#pragma unroll
      for (int p = 0; p < 4; p++) {
        int F = p * 4 + w;
        stA[p] = *reinterpret_cast<const uint4*>(
            w1t + (size_t)(nn + (F >> 3) * 32 + ln) * 128 + (F & 7) * 16 + hi * 8);
        stB[p] = *reinterpret_cast<const uint4*>(
            w2t + (size_t)((F >> 2) * 32 + ln) * 65536 + nn + (F & 3) * 16 + hi * 8);
      }
    }
    int n0 = chunk * 2048 + t * 64;
    const unsigned short* A = &lA[cur][0][0];
    const unsigned short* B = &lB[cur][0][0];
#pragma unroll
    for (int sub = 0; sub < 2; sub++) {
      // GEMM1': Gt[n 32][m 32] per m-tile ; K = e = 128
      f32x16 g0 = zero16(), g1 = zero16();
#pragma unroll
      for (int kk = 0; kk < 8; kk++) {
        bf16x8 a = *reinterpret_cast<const bf16x8*>(A + (sub * 8 + kk) * 512 + l * 8);
        g0 = MFMA(a, hb[0][kk], g0);
        g1 = MFMA(a, hb[1][kk], g1);
      }
      // bias + relu in-register (row r -> n-local (r&3)+8*(r>>2)+4*hi)
#pragma unroll
      for (int r = 0; r < 16; r++) {
        float bv = bf1[n0 + sub * 32 + (r & 3) + 8 * (r >> 2) + 4 * hi];
        g0[r] = fmaxf(g0[r] + bv, 0.f);
        g1[r] = fmaxf(g1[r] + bv, 0.f);
      }
      // H-fragments (lane = m-local, k = n-slice) via cvt_pk+permlane
      bf16x8 pb00 = pfrag(g0[0], g0[1], g0[2], g0[3], g0[4], g0[5], g0[6], g0[7]);
      bf16x8 pb01 = pfrag(g0[8], g0[9], g0[10], g0[11], g0[12], g0[13], g0[14], g0[15]);
      bf16x8 pb10 = pfrag(g1[0], g1[1], g1[2], g1[3], g1[4], g1[5], g1[6], g1[7]);
      bf16x8 pb11 = pfrag(g1[8], g1[9], g1[10], g1[11], g1[12], g1[13], g1[14], g1[15]);
      // GEMM2: out[m 32][e 128] += H-as-A x W2-as-B ; each W2 frag feeds 2 MFMAs
#pragma unroll
      for (int et = 0; et < 4; et++) {
        bf16x8 wa0 = *reinterpret_cast<const bf16x8*>(B + (et * 4 + sub * 2 + 0) * 512 + l * 8);
        acc[et][0] = MFMA(pb00, wa0, acc[et][0]);
        acc[et][1] = MFMA(pb10, wa0, acc[et][1]);
        bf16x8 wa1 = *reinterpret_cast<const bf16x8*>(B + (et * 4 + sub * 2 + 1) * 512 + l * 8);
        acc[et][0] = MFMA(pb01, wa1, acc[et][0]);
        acc[et][1] = MFMA(pb11, wa1, acc[et][1]);
      }
      if (sub == 0 && t < 31) {  // write staged regs mid-iter (other buffer: no hazard)
#pragma unroll
        for (int p = 0; p < 4; p++) {
          int F = p * 4 + w;
          *reinterpret_cast<uint4*>(&lA[cur ^ 1][F][l * 8]) = stA[p];
          *reinterpret_cast<uint4*>(&lB[cur ^ 1][F][l * 8]) = stB[p];
        }
      }
    }
    __syncthreads();
    cur ^= 1;
  }
  // epilogue: lane ln = e (consecutive) -> coalesced atomics
#pragma unroll
  for (int et = 0; et < 4; et++)
#pragma unroll
    for (int mh = 0; mh < 2; mh++)
#pragma unroll
      for (int r = 0; r < 16; r++) {
        int m = m0 + mh * 32 + (r & 3) + 8 * (r >> 2) + 4 * hi;
        atomicAdd(&outp[(size_t)m * 128 + et * 32 + ln], acc[et][mh][r]);
      }
}

extern "C" void kernel_launch(void* const* d_in, const int* in_sizes, int n_in,
                              void* d_out, int out_size, void* d_ws, size_t ws_size,
                              hipStream_t stream) {
  (void)in_sizes; (void)n_in; (void)out_size; (void)ws_size;
  const float* x = (const float*)d_in[0];
  const float* Wk = (const float*)d_in[1];
  const float* Wq = (const float*)d_in[2];
  const float* Wv = (const float*)d_in[3];
  const float* Wo = (const float*)d_in[4];
  const float* bo = (const float*)d_in[5];
  const float* g1 = (const float*)d_in[6];
  const float* be1 = (const float*)d_in[7];
  const float* g2 = (const float*)d_in[8];
  const float* be2 = (const float*)d_in[9];
  const float* W1 = (const float*)d_in[10];
  const float* bf1 = (const float*)d_in[11];
  const float* W2 = (const float*)d_in[12];
  const float* bf2 = (const float*)d_in[13];
  float* outp = (float*)d_out;

  unsigned short* ws = (unsigned short*)d_ws;
  unsigned short* W1t = ws;                       // [65536][128] bf16
  unsigned short* W2t = ws + 8388608;             // [128][65536] bf16
  unsigned short* Wqkvt = ws + 16777216;          // [384][128]
  unsigned short* Wot = ws + 16826368;            // [128][128]
  unsigned short* h1 = ws + 16842752;             // [4096][128]
  unsigned short* h2 = ws + 17367040;             // [4096][128]
  unsigned short* qw = ws + 17891328;             // [16][2048][16]
  unsigned short* kw = ws + 18415616;
  unsigned short* vw = ws + 18939904;
  unsigned short* ow = ws + 19464192;             // [4096][128]
  float* x1 = (float*)(ws + 19988480);            // [4096][128] f32

  k_transpose<<<dim3(2048, 4), dim3(32, 8), 0, stream>>>(W1, W1t, 128, 65536);
  k_transpose<<<dim3(4, 2048), dim3(32, 8), 0, stream>>>(W2, W2t, 65536, 128);
  k_build_qkvo<<<256, 256, 0, stream>>>(Wq, Wk, Wv, Wo, Wqkvt, Wot);
  k_ln<<<1024, 256, 0, stream>>>(x, g1, be1, h1);
  k_gemm_qkv<<<dim3(32, 3), 256, 0, stream>>>(h1, Wqkvt, qw);
  k_attn2<<<dim3(16, 16), 256, 0, stream>>>(qw, kw, vw, ow);
  k_gemm_proj<<<32, 256, 0, stream>>>(ow, Wot, bo, x, bf2, x1, outp);
  k_ln<<<1024, 256, 0, stream>>>(x1, g2, be2, h2);
  k_ffn4<<<512, 256, 0, stream>>>(h2, W1t, W2t, bf1, outp);
}